// Round 9
// baseline (109.762 us; speedup 1.0000x reference)
//
#include <hip/hip_runtime.h>
#include <cmath>

// Problem constants
constexpr int Bb  = 2;
constexpr int Nn  = 2048;
constexpr int Dd  = 1024;
constexpr int Hh  = 16;
constexpr int HDd = 64;

// 0.125 (softmax scale) * log2(e), folded into Q at the QKV epilogue
#define QSCALE 0.18033688011112042f

typedef __attribute__((ext_vector_type(8))) _Float16 f16x8;
typedef __attribute__((ext_vector_type(2))) __fp16   fp16x2;
typedef __attribute__((ext_vector_type(4))) float    f32x4;

__device__ inline unsigned short f2h(float f) {    // f32 -> f16 RTN
  _Float16 h = (_Float16)f;
  union { _Float16 h; unsigned short u; } v; v.h = h; return v.u;
}
__device__ inline unsigned cvt_pk_f16(float x, float y) {  // 2xf32 -> packed f16 (RTZ)
  union { fp16x2 h; unsigned u; } v;
  v.h = __builtin_amdgcn_cvt_pkrtz(x, y);
  return v.u;
}
// Single-instruction exp2
__device__ inline float fexp2(float x) {
  float r;
  asm("v_exp_f32 %0, %1" : "=v"(r) : "v"(x));
  return r;
}
__device__ inline void gload16(const void* g, void* l) {
  __builtin_amdgcn_global_load_lds((const __attribute__((address_space(1))) void*)g,
                                   (__attribute__((address_space(3))) void*)l, 16, 0, 0);
}

// ---------------------------------------------------------------------------
// Fused prep: blocks [0,2048) xcast; [2048,2816) w_qkv T+cast; [2816,3072) w_proj
// ---------------------------------------------------------------------------
__global__ __launch_bounds__(256) void prep(
    const float* __restrict__ X, const float* __restrict__ Wq,
    const float* __restrict__ Wp,
    unsigned short* __restrict__ Xf, unsigned short* __restrict__ Bqt,
    unsigned short* __restrict__ Bpt)
{
  const int bid = blockIdx.x;
  const int t = threadIdx.x;

  if (bid < 2048) {   // ---- xcast: 8 f32 -> f16 per thread
    const size_t i = ((size_t)bid * 256 + t) * 8;
    float4 u0 = *(const float4*)(X + i);
    float4 u1 = *(const float4*)(X + i + 4);
    ushort4 a, b;
    a.x = f2h(u0.x); a.y = f2h(u0.y); a.z = f2h(u0.z); a.w = f2h(u0.w);
    b.x = f2h(u1.x); b.y = f2h(u1.y); b.z = f2h(u1.z); b.w = f2h(u1.w);
    *(ushort4*)(Xf + i)     = a;
    *(ushort4*)(Xf + i + 4) = b;
    return;
  }

  __shared__ float T[64][65];
  const float* W; unsigned short* Wt; int Nd, n0, k0;
  if (bid < 2816) {
    const int b2 = bid - 2048;          // 768 blocks: 48 x 16
    W = Wq; Wt = Bqt; Nd = 3 * Dd;
    n0 = (b2 % 48) * 64; k0 = (b2 / 48) * 64;
  } else {
    const int b3 = bid - 2816;          // 256 blocks: 16 x 16
    W = Wp; Wt = Bpt; Nd = Dd;
    n0 = (b3 & 15) * 64; k0 = (b3 >> 4) * 64;
  }
  const int Kd = Dd;
#pragma unroll
  for (int i = 0; i < 4; ++i) {
    int idx = t + 256 * i;
    int r = idx >> 4, c4 = (idx & 15) * 4;
    float4 v = *(const float4*)(W + (size_t)(k0 + r) * Nd + n0 + c4);
    T[c4 + 0][r] = v.x; T[c4 + 1][r] = v.y;
    T[c4 + 2][r] = v.z; T[c4 + 3][r] = v.w;
  }
  __syncthreads();
#pragma unroll
  for (int i = 0; i < 4; ++i) {
    int idx = t + 256 * i;
    int nr = idx >> 4, kc = (idx & 15) * 4;
    ushort4 hv;
    hv.x = f2h(T[nr][kc + 0]); hv.y = f2h(T[nr][kc + 1]);
    hv.z = f2h(T[nr][kc + 2]); hv.w = f2h(T[nr][kc + 3]);
    *(ushort4*)(Wt + (size_t)(n0 + nr) * Kd + k0 + kc) = hv;
  }
}

// ---------------------------------------------------------------------------
// QKV GEMM, R27: verified 128x128 R12/R21 core converted to a counted-vmcnt
// double-buffered pipeline (the ONLY change is the sync structure):
//   per K-step: stage(next buf, 8 gloads/wave) -> s_waitcnt vmcnt(8)
//   (waits ONLY for the current step's 8 oldest loads; never drains) ->
//   raw s_barrier -> compute (C++ ds_reads, compiler-managed lgkm) ->
//   raw s_barrier (WAR; no drain).  Last step waits vmcnt(0).
// Race analysis: buf written at iteration top was last read before the END
// barrier of the PREVIOUS iteration; per-wave vmcnt(8)+barrier => all waves'
// step-ks loads landed before any read of them.  sched_barrier(0) pins
// LDS reads behind the barriers.
// LDS 64 KB dbuf -> 2 blocks/CU.  Grid 768 (XCD-swizzled).  EPI-1 epilogue
// (per-head Qf/Kf +QSCALE, sigma-permuted Vtf) unchanged.
// ---------------------------------------------------------------------------
__global__ __launch_bounds__(256, 2) void gemm_qkv_cv(
    const unsigned short* __restrict__ Ag,
    const unsigned short* __restrict__ Bg,
    const float* __restrict__ bias,
    unsigned short* __restrict__ Qf, unsigned short* __restrict__ Kf,
    unsigned short* __restrict__ Vtf,
    int Ksz, int gridM)
{
  __shared__ __align__(16) unsigned short A_s[16384];  // 2 x [128 rows][64 k]
  __shared__ __align__(16) unsigned short B_s[16384];  // 2 x [128 cols][64 k]

  const int t    = threadIdx.x;
  const int lane = t & 63, w = t >> 6;
  const int g = lane >> 4, lid = lane & 15;
  const int wr = w >> 1, wc = w & 1;

  const int nwg = gridDim.x;
  const int per = nwg >> 3;
  const int bid = (blockIdx.x & 7) * per + (blockIdx.x >> 3);
  const int by = bid % gridM, bx = bid / gridM;
  const int row0 = by * 128, col0 = bx * 128;

  f32x4 acc[4][4];
#pragma unroll
  for (int i = 0; i < 4; ++i)
#pragma unroll
    for (int j = 0; j < 4; ++j) acc[i][j] = f32x4{0.f, 0.f, 0.f, 0.f};

  const int sg8 = ((lane & 7) ^ (lane >> 3)) * 8;  // pre-swizzled src chunk
  const int rl8 = lane >> 3;                        // row within octet
  const int l7 = lid & 7;

  // Hoisted LDS read bases (row&7 == lid&7 for every fragment row)
  const unsigned short* bA[2] = {
    A_s + (wr * 64 + lid) * 64 + (((0 + g) ^ l7) << 3),
    A_s + (wr * 64 + lid) * 64 + (((4 + g) ^ l7) << 3) };
  const unsigned short* bB[2] = {
    B_s + (wc * 64 + lid) * 64 + (((0 + g) ^ l7) << 3),
    B_s + (wc * 64 + lid) * 64 + (((4 + g) ^ l7) << 3) };

  // Stage one full K-step (8 gloads per wave: 4 A octets + 4 B octets)
  auto stageAB = [&](int buf, int k0) {
#pragma unroll
    for (int q = 0; q < 4; ++q) {
      const int oct = w * 4 + q;        // 0..15
      const int r = oct * 8 + rl8;      // 0..127
      gload16(Ag + (size_t)(row0 + r) * Ksz + k0 + sg8, A_s + buf * 8192 + oct * 512);
      gload16(Bg + (size_t)(col0 + r) * Ksz + k0 + sg8, B_s + buf * 8192 + oct * 512);
    }
  };

  // Compute one K-step from buffer at literal short-offset KB
  auto compute = [&](int KB) __attribute__((always_inline)) {
#pragma unroll
    for (int kk = 0; kk < 2; ++kk) {
      f16x8 a[4], b[4];
#pragma unroll
      for (int mb = 0; mb < 4; ++mb)
        a[mb] = *(const f16x8*)(bA[kk] + KB + mb * 1024);
#pragma unroll
      for (int nb = 0; nb < 4; ++nb)
        b[nb] = *(const f16x8*)(bB[kk] + KB + nb * 1024);
      __builtin_amdgcn_s_setprio(1);
#pragma unroll
      for (int mb = 0; mb < 4; ++mb)
#pragma unroll
        for (int nb = 0; nb < 4; ++nb)
          acc[mb][nb] = __builtin_amdgcn_mfma_f32_16x16x32_f16(a[mb], b[nb], acc[mb][nb], 0, 0, 0);
      __builtin_amdgcn_s_setprio(0);
    }
  };

  const int nk = Ksz >> 6;              // 16 K-steps (even)
  stageAB(0, 0);                        // prologue: step 0 into buf0

  for (int t2 = 0; t2 < nk / 2; ++t2) {
    const int ks = 2 * t2;
    // ---- even step ks: buf0.  ks <= 14, so ks+1 always exists.
    stageAB(1, (ks + 1) * 64);
    asm volatile("s_waitcnt vmcnt(8)" ::: "memory");   // step-ks loads landed
    __builtin_amdgcn_s_barrier();
    __builtin_amdgcn_sched_barrier(0);
    compute(0);
    __builtin_amdgcn_sched_barrier(0);
    __builtin_amdgcn_s_barrier();                      // WAR: buf0 reads done

    // ---- odd step ks+1: buf1
    if (ks + 2 < nk) {
      stageAB(0, (ks + 2) * 64);
      asm volatile("s_waitcnt vmcnt(8)" ::: "memory");
    } else {
      asm volatile("s_waitcnt vmcnt(0)" ::: "memory"); // final drain
    }
    __builtin_amdgcn_s_barrier();
    __builtin_amdgcn_sched_barrier(0);
    compute(8192);
    __builtin_amdgcn_sched_barrier(0);
    __builtin_amdgcn_s_barrier();                      // WAR: buf1 reads done
  }

  // Epilogue: per-head Qf/Kf (+QSCALE) + sigma-permuted Vtf (verified algebra)
#pragma unroll
  for (int nb = 0; nb < 4; ++nb) {
    const int cg = col0 + wc * 64 + nb * 16 + lid;
    const float bv = bias[cg];
    const int region = cg >> 10;          // 0=Q 1=K 2=V
    const int h  = (cg & 1023) >> 6;
    const int hd = cg & 63;
    const int b2 = row0 >> 11;
    const int bh_ = b2 * Hh + h;
    const float sc = (region == 0) ? QSCALE : 1.0f;
#pragma unroll
    for (int mb = 0; mb < 4; ++mb) {
      const int nt0 = (row0 & 2047) + wr * 64 + mb * 16 + 4 * g;
      float cc[4];
#pragma unroll
      for (int reg = 0; reg < 4; ++reg) cc[reg] = (acc[mb][nb][reg] + bv) * sc;
      if (region == 2) {
        // sigma kv-permutation (nt0 is a multiple of 4: r-bits pass through)
        const int ns = (nt0 & ~31) | ((nt0 & 12) << 1) | ((nt0 & 16) >> 2);
        ushort4 vv;
        vv.x = f2h(cc[0]); vv.y = f2h(cc[1]);
        vv.z = f2h(cc[2]); vv.w = f2h(cc[3]);
        *(ushort4*)(Vtf + ((size_t)bh_ * HDd + hd) * Nn + ns) = vv;
      } else {
        unsigned short* P = (region == 0) ? Qf : Kf;
#pragma unroll
        for (int reg = 0; reg < 4; ++reg)
          P[((size_t)bh_ * Nn + nt0 + reg) * HDd + hd] = f2h(cc[reg]);
      }
    }
  }
}

// ---------------------------------------------------------------------------
// Proj GEMM (verified R21 config): 64x128 tile, 4 waves as 1x4 col-groups,
// BK=64, single-buffer LDS, hoisted read bases, fp32 out. 512 blocks = 2/CU.
// ---------------------------------------------------------------------------
__global__ __launch_bounds__(256, 4) void gemm_proj(
    const unsigned short* __restrict__ Ag,
    const unsigned short* __restrict__ Bg,
    const float* __restrict__ bias,
    float* __restrict__ Cout,
    int Nsz, int Ksz, int gridM)
{
  __shared__ __align__(16) unsigned short A_s[4096];   // 64 rows x 64 k
  __shared__ __align__(16) unsigned short B_s[8192];   // 128 cols x 64 k

  const int t    = threadIdx.x;
  const int lane = t & 63, w = t >> 6;
  const int g = lane >> 4, lid = lane & 15;
  const int wcol0 = w * 32;

  const int nwg = gridDim.x;
  const int per = nwg >> 3;
  const int bid = (blockIdx.x & 7) * per + (blockIdx.x >> 3);
  const int by = bid % gridM, bx = bid / gridM;
  const int row0 = by * 64, col0 = bx * 128;

  f32x4 acc[4][2];
#pragma unroll
  for (int i = 0; i < 4; ++i)
#pragma unroll
    for (int j = 0; j < 2; ++j) acc[i][j] = f32x4{0.f, 0.f, 0.f, 0.f};

  const int sg8 = ((lane & 7) ^ (lane >> 3)) * 8;
  const int rl8 = lane >> 3;
  const int l7 = lid & 7;

  const unsigned short* bA[2] = {
    A_s + lid * 64 + (((0 + g) ^ l7) << 3),
    A_s + lid * 64 + (((4 + g) ^ l7) << 3) };
  const unsigned short* bB[2] = {
    B_s + (wcol0 + lid) * 64 + (((0 + g) ^ l7) << 3),
    B_s + (wcol0 + lid) * 64 + (((4 + g) ^ l7) << 3) };

  for (int k0 = 0; k0 < Ksz; k0 += 64) {
#pragma unroll
    for (int q = 0; q < 2; ++q) {       // A: 8 octets (64 rows)
      const int oct = w * 2 + q;
      const int r = oct * 8 + rl8;
      gload16(Ag + (size_t)(row0 + r) * Ksz + k0 + sg8, A_s + oct * 512);
    }
#pragma unroll
    for (int q = 0; q < 4; ++q) {       // B: 16 octets (128 cols)
      const int oct = w * 4 + q;
      const int r = oct * 8 + rl8;
      gload16(Bg + (size_t)(col0 + r) * Ksz + k0 + sg8, B_s + oct * 512);
    }
    __syncthreads();

#pragma unroll
    for (int kk = 0; kk < 2; ++kk) {
      f16x8 a[4], b[2];
#pragma unroll
      for (int mb = 0; mb < 4; ++mb)
        a[mb] = *(const f16x8*)(bA[kk] + mb * 1024);
#pragma unroll
      for (int nb = 0; nb < 2; ++nb)
        b[nb] = *(const f16x8*)(bB[kk] + nb * 1024);
#pragma unroll
      for (int mb = 0; mb < 4; ++mb)
#pragma unroll
        for (int nb = 0; nb < 2; ++nb)
          acc[mb][nb] = __builtin_amdgcn_mfma_f32_16x16x32_f16(a[mb], b[nb], acc[mb][nb], 0, 0, 0);
    }
    __syncthreads();
  }

#pragma unroll
  for (int nb = 0; nb < 2; ++nb) {
    const int cg = col0 + wcol0 + nb * 16 + lid;
    const float bv = bias[cg];
#pragma unroll
    for (int mb = 0; mb < 4; ++mb)
#pragma unroll
      for (int reg = 0; reg < 4; ++reg) {
        int nrow = row0 + mb * 16 + 4 * g + reg;
        Cout[(size_t)nrow * Nsz + cg] = acc[mb][nb][reg] + bv;
      }
  }
}

// ---------------------------------------------------------------------------
// MFMA flash attention, R23 (verified 42.5us): within-tile 4-phase order,
// loop-invariant zero C-operand, 6 hoisted LDS bases, x2-unrolled tile loop
// (all ds_read_b128 are base + imm16). P never touches LDS (sigma-permuted
// V, cvt_pk packs straight to PV A-frags). Dual q-strip per wave, 4 waves,
// Q-tile 128, grid 512, KVBLK=128, dbuf, max-free softmax, ones-MFMA
// denominator. LDS 64 KB.
// ---------------------------------------------------------------------------
__global__ __launch_bounds__(256, 2) void attn_mfma(
    const unsigned short* __restrict__ Qf, const unsigned short* __restrict__ Kf,
    const unsigned short* __restrict__ Vt,
    unsigned short* __restrict__ Of)
{
  __shared__ __align__(16) unsigned short Kf_s[16384];    // 2 x [128 kv][64 k]
  __shared__ __align__(16) unsigned short Vt_s[16384];    // 2 x [64 d][128 kv sigma]

  const int t    = threadIdx.x;
  const int lane = t & 63, w = t >> 6;        // 4 waves
  const int g    = lane >> 4, lid = lane & 15;

  const int hw = blockIdx.x;                  // 512 blocks
  const int bh = (hw & 7) * 4 + ((hw >> 3) & 3);
  const int q0 = (hw >> 5) * 128;             // 16 q-blocks per head
  const int b_ = bh >> 4, h_ = bh & 15;

  const size_t kvbase = (size_t)bh * Nn * HDd;

  // Hoisted Q for both strips (B-frag: col=lid, k=g*8+j)
  const int qrowA = q0 + w * 16 + lid;
  const unsigned short* qpA = Qf + kvbase + (size_t)qrowA * HDd + g * 8;
  f16x8 qa0 = *(const f16x8*)(qpA);
  f16x8 qa1 = *(const f16x8*)(qpA + 32);
  const unsigned short* qpB = qpA + (size_t)64 * HDd;
  f16x8 qb0 = *(const f16x8*)(qpB);
  f16x8 qb1 = *(const f16x8*)(qpB + 32);

  f16x8 vones;
#pragma unroll
  for (int i = 0; i < 8; ++i) vones[i] = (_Float16)1.0f;

  // Loop-invariant zero C-operand (kills per-tile accumulator zero-init)
  const f32x4 fz0 = f32x4{0.f, 0.f, 0.f, 0.f};

  f32x4 oA[4], oB[4];
  f32x4 olA = f32x4{0.f, 0.f, 0.f, 0.f};
  f32x4 olB = f32x4{0.f, 0.f, 0.f, 0.f};
#pragma unroll
  for (int i = 0; i < 4; ++i) { oA[i] = f32x4{0.f,0.f,0.f,0.f}; oB[i] = f32x4{0.f,0.f,0.f,0.f}; }

  const int sg8 = ((lane & 7) ^ (lane >> 3)) * 8;  // K staging src chunk
  const int l7  = lid & 7;
  const int l15 = lid & 15;

  // Hoisted LDS read bases (all ds_reads become base + literal offset)
  const unsigned short* bK0 = Kf_s + lid * 64 + (((0 + g) ^ l7) << 3);
  const unsigned short* bK1 = Kf_s + lid * 64 + (((4 + g) ^ l7) << 3);
  const unsigned short* bV00 = Vt_s + lid * 128 + (((0  + g) ^ l15) << 3);
  const unsigned short* bV01 = Vt_s + lid * 128 + (((4  + g) ^ l15) << 3);
  const unsigned short* bV10 = Vt_s + lid * 128 + (((8  + g) ^ l15) << 3);
  const unsigned short* bV11 = Vt_s + lid * 128 + (((12 + g) ^ l15) << 3);

  auto stage = [&](int buf, int kv0) {
#pragma unroll
    for (int q = 0; q < 8; ++q) {
      const int idx = w * 8 + q;            // 0..31 (wave-uniform branch)
      if (idx < 16) {                       // K: octet of 8 kv-rows
        const int r = idx * 8 + (lane >> 3);
        gload16(Kf + kvbase + (size_t)(kv0 + r) * HDd + sg8,
                Kf_s + buf * 8192 + idx * 512);
      } else {                              // V: quad of 4 d-rows, 16 chunks
        const int qd = idx - 16;
        const int r = qd * 4 + (lane >> 4);
        const int srcc = (lane & 15) ^ (r & 15);
        gload16(Vt + kvbase + (size_t)r * Nn + kv0 + srcc * 8,
                Vt_s + buf * 8192 + qd * 512);
      }
    }
  };

  union PU { unsigned u[4]; f16x8 v; };

  auto tile_compute = [&](int KB) __attribute__((always_inline)) {
    f32x4 sA[8], sB[8];

    // ---- P1: QK h0 (jbb 0..3)
    __builtin_amdgcn_s_setprio(1);
#pragma unroll
    for (int jbb = 0; jbb < 4; ++jbb) {
      f16x8 kf0 = *(const f16x8*)(bK0 + KB + jbb * 1024);
      f16x8 kf1 = *(const f16x8*)(bK1 + KB + jbb * 1024);
      sA[jbb] = __builtin_amdgcn_mfma_f32_16x16x32_f16(kf0, qa0, fz0, 0, 0, 0);
      sA[jbb] = __builtin_amdgcn_mfma_f32_16x16x32_f16(kf1, qa1, sA[jbb], 0, 0, 0);
      sB[jbb] = __builtin_amdgcn_mfma_f32_16x16x32_f16(kf0, qb0, fz0, 0, 0, 0);
      sB[jbb] = __builtin_amdgcn_mfma_f32_16x16x32_f16(kf1, qb1, sB[jbb], 0, 0, 0);
    }
    __builtin_amdgcn_s_setprio(0);

    // ---- P2: QK h1 (jbb 4..7) interleaved with exp/pack h0
    PU pA0, pA1, pB0, pB1;
#pragma unroll
    for (int j = 0; j < 4; ++j) {
      const int jbb = 4 + j;
      f16x8 kf0 = *(const f16x8*)(bK0 + KB + jbb * 1024);
      f16x8 kf1 = *(const f16x8*)(bK1 + KB + jbb * 1024);
      sA[jbb] = __builtin_amdgcn_mfma_f32_16x16x32_f16(kf0, qa0, fz0, 0, 0, 0);
      sA[jbb] = __builtin_amdgcn_mfma_f32_16x16x32_f16(kf1, qa1, sA[jbb], 0, 0, 0);
      sB[jbb] = __builtin_amdgcn_mfma_f32_16x16x32_f16(kf0, qb0, fz0, 0, 0, 0);
      sB[jbb] = __builtin_amdgcn_mfma_f32_16x16x32_f16(kf1, qb1, sB[jbb], 0, 0, 0);
#pragma unroll
      for (int reg = 0; reg < 4; ++reg) {
        sA[j][reg] = fexp2(sA[j][reg]);
        sB[j][reg] = fexp2(sB[j][reg]);
      }
      if (j == 1) {
        pA0.u[0] = cvt_pk_f16(sA[0][0], sA[0][1]); pA0.u[1] = cvt_pk_f16(sA[0][2], sA[0][3]);
        pA0.u[2] = cvt_pk_f16(sA[1][0], sA[1][1]); pA0.u[3] = cvt_pk_f16(sA[1][2], sA[1][3]);
        pB0.u[0] = cvt_pk_f16(sB[0][0], sB[0][1]); pB0.u[1] = cvt_pk_f16(sB[0][2], sB[0][3]);
        pB0.u[2] = cvt_pk_f16(sB[1][0], sB[1][1]); pB0.u[3] = cvt_pk_f16(sB[1][2], sB[1][3]);
      }
      if (j == 3) {
        pA1.u[0] = cvt_pk_f16(sA[2][0], sA[2][1]); pA1.u[1] = cvt_pk_f16(sA[2][2], sA[2][3]);
        pA1.u[2] = cvt_pk_f16(sA[3][0], sA[3][1]); pA1.u[3] = cvt_pk_f16(sA[3][2], sA[3][3]);
        pB1.u[0] = cvt_pk_f16(sB[2][0], sB[2][1]); pB1.u[1] = cvt_pk_f16(sB[2][2], sB[2][3]);
        pB1.u[2] = cvt_pk_f16(sB[3][0], sB[3][1]); pB1.u[3] = cvt_pk_f16(sB[3][2], sB[3][3]);
      }
    }

    // ---- P3: PV h0 interleaved with exp/pack h1
    PU qA0, qA1, qB0, qB1;
    olA = __builtin_amdgcn_mfma_f32_16x16x32_f16(pA0.v, vones, olA, 0, 0, 0);
    olA = __builtin_amdgcn_mfma_f32_16x16x32_f16(pA1.v, vones, olA, 0, 0, 0);
    olB = __builtin_amdgcn_mfma_f32_16x16x32_f16(pB0.v, vones, olB, 0, 0, 0);
    olB = __builtin_amdgcn_mfma_f32_16x16x32_f16(pB1.v, vones, olB, 0, 0, 0);
#pragma unroll
    for (int cb = 0; cb < 4; ++cb) {
      f16x8 vb0 = *(const f16x8*)(bV00 + KB + cb * 2048);
      f16x8 vb1 = *(const f16x8*)(bV01 + KB + cb * 2048);
      oA[cb] = __builtin_amdgcn_mfma_f32_16x16x32_f16(pA0.v, vb0, oA[cb], 0, 0, 0);
      oA[cb] = __builtin_amdgcn_mfma_f32_16x16x32_f16(pA1.v, vb1, oA[cb], 0, 0, 0);
      oB[cb] = __builtin_amdgcn_mfma_f32_16x16x32_f16(pB0.v, vb0, oB[cb], 0, 0, 0);
      oB[cb] = __builtin_amdgcn_mfma_f32_16x16x32_f16(pB1.v, vb1, oB[cb], 0, 0, 0);
#pragma unroll
      for (int reg = 0; reg < 4; ++reg) {
        sA[4 + cb][reg] = fexp2(sA[4 + cb][reg]);
        sB[4 + cb][reg] = fexp2(sB[4 + cb][reg]);
      }
      if (cb == 1) {
        qA0.u[0] = cvt_pk_f16(sA[4][0], sA[4][1]); qA0.u[1] = cvt_pk_f16(sA[4][2], sA[4][3]);
        qA0.u[2] = cvt_pk_f16(sA[5][0], sA[5][1]); qA0.u[3] = cvt_pk_f16(sA[5][2], sA[5][3]);
        qB0.u[0] = cvt_pk_f16(sB[4][0], sB[4][1]); qB0.u[1] = cvt_pk_f16(sB[4][2], sB[4][3]);
        qB0.u[2] = cvt_pk_f16(sB[5][0], sB[5][1]); qB0.u[3] = cvt_pk_f16(sB[5][2], sB[5][3]);
      }
      if (cb == 3) {
        qA1.u[0] = cvt_pk_f16(sA[6][0], sA[6][1]); qA1.u[1] = cvt_pk_f16(sA[6][2], sA[6][3]);
        qA1.u[2] = cvt_pk_f16(sA[7][0], sA[7][1]); qA1.u[3] = cvt_pk_f16(sA[7][2], sA[7][3]);
        qB1.u[0] = cvt_pk_f16(sB[6][0], sB[6][1]); qB1.u[1] = cvt_pk_f16(sB[6][2], sB[6][3]);
        qB1.u[2] = cvt_pk_f16(sB[7][0], sB[7][1]); qB1.u[3] = cvt_pk_f16(sB[7][2], sB[7][3]);
      }
    }

    // ---- P4: PV h1
    __builtin_amdgcn_s_setprio(1);
    olA = __builtin_amdgcn_mfma_f32_16x16x32_f16(qA0.v, vones, olA, 0, 0, 0);
    olA = __builtin_amdgcn_mfma_f32_16x16x32_f16(qA1.v, vones, olA, 0, 0, 0);
    olB = __builtin_amdgcn_mfma_f32_16x16x32_f16(qB0.v, vones, olB, 0, 0, 0);
    olB = __builtin_amdgcn_mfma_f32_16x16x32_f16(qB1.v, vones, olB, 0, 0, 0);
#pragma unroll
    for (int cb = 0; cb < 4; ++cb) {
      f16x8 vb0 = *(const f16x8*)(bV10 + KB + cb * 2048);
      f16x8 vb1 = *(const f16x8*)(bV11 + KB + cb * 2048);
      oA[cb] = __builtin_amdgcn_mfma_f32_16x16x32_f16(qA0.v, vb0, oA[cb], 0, 0, 0);
      oA[cb] = __builtin_amdgcn_mfma_f32_16x16x32_f16(qA1.v, vb1, oA[cb], 0, 0, 0);
      oB[cb] = __builtin_amdgcn_mfma_f32_16x16x32_f16(qB0.v, vb0, oB[cb], 0, 0, 0);
      oB[cb] = __builtin_amdgcn_mfma_f32_16x16x32_f16(qB1.v, vb1, oB[cb], 0, 0, 0);
    }
    __builtin_amdgcn_s_setprio(0);
  };

  stage(0, 0);
  const int NT = Nn / 128;              // 16 (even)

  for (int t2 = 0; t2 < NT / 2; ++t2) {
    const int tt0 = 2 * t2;
    __syncthreads();                    // buf0 staged; prior buf1 reads done
    stage(1, (tt0 + 1) * 128);
    tile_compute(0);
    __syncthreads();                    // buf1 staged; prior buf0 reads done
    if (t2 < NT / 2 - 1) stage(0, (tt0 + 2) * 128);
    tile_compute(8192);
  }

  // ---- epilogue: normalize both strips (l in row layout from ones-MFMA)
  const size_t obaseA = ((size_t)(b_ * Nn + q0 + w * 16)) * Dd + h_ * 64;
  const size_t obaseB = obaseA + (size_t)64 * Dd;
#pragma unroll
  for (int reg = 0; reg < 4; ++reg) {
    const int row = 4 * g + reg;
    const float ivA = 1.0f / olA[reg];
    const float ivB = 1.0f / olB[reg];
#pragma unroll
    for (int cb = 0; cb < 4; ++cb) {
      Of[obaseA + (size_t)row * Dd + cb * 16 + lid] = f2h(oA[cb][reg] * ivA);
      Of[obaseB + (size_t)row * Dd + cb * 16 + lid] = f2h(oB[cb][reg] * ivB);
    }
  }
}

// ---------------------------------------------------------------------------
extern "C" void kernel_launch(void* const* d_in, const int* in_sizes, int n_in,
                              void* d_out, int out_size, void* d_ws, size_t ws_size,
                              hipStream_t stream)
{
  const float* x      = (const float*)d_in[0];
  const float* w_qkv  = (const float*)d_in[1];
  const float* b_qkv  = (const float*)d_in[2];
  const float* w_proj = (const float*)d_in[3];
  const float* b_proj = (const float*)d_in[4];
  float* outp = (float*)d_out;

  unsigned char* ws = (unsigned char*)d_ws;
  const size_t MB = 1ull << 20;
  unsigned short* Xf  = (unsigned short*)(ws +  0 * MB);  // 8 MB f16
  unsigned short* Bqt = (unsigned short*)(ws +  8 * MB);  // 6 MB f16 [3072][1024]
  unsigned short* Qf  = (unsigned short*)(ws + 14 * MB);  // 8 MB
  unsigned short* Kf  = (unsigned short*)(ws + 22 * MB);  // 8 MB
  unsigned short* Vtf = (unsigned short*)(ws + 30 * MB);  // 8 MB (sigma-permuted kv)
  unsigned short* Ofb = (unsigned short*)(ws + 38 * MB);  // 8 MB
  unsigned short* Bpt = (unsigned short*)(ws + 46 * MB);  // 2 MB [1024][1024]

  const int M = Bb * Nn;  // 4096

  // 1) fused prep: x->f16, w_qkv/w_proj -> transposed f16
  prep<<<dim3(3072), 256, 0, stream>>>(x, w_qkv, w_proj, Xf, Bqt, Bpt);

  // 2) QKV GEMM (128x128, counted-vmcnt dbuf pipeline; 768 blocks)
  gemm_qkv_cv<<<dim3((3 * Dd / 128) * (M / 128)), 256, 0, stream>>>(
      Xf, Bqt, b_qkv, Qf, Kf, Vtf, Dd, M / 128);

  // 3) flash attention -> Of (f16); 512 blocks x 256 threads, Q-tile 128
  attn_mfma<<<dim3((Nn / 128) * Bb * Hh), 256, 0, stream>>>(Qf, Kf, Vtf, Ofb);

  // 4) proj GEMM (64x128 tiles, 512 blocks = 2/CU) -> fp32 out
  gemm_proj<<<dim3((Dd / 128) * (M / 64)), 256, 0, stream>>>(
      Ofb, Bpt, b_proj, outp, Dd, Dd, M / 64);
}

// Round 10
// 100.388 us; speedup vs baseline: 1.0934x; 1.0934x over previous
//
#include <hip/hip_runtime.h>
#include <cmath>

// Problem constants
constexpr int Bb  = 2;
constexpr int Nn  = 2048;
constexpr int Dd  = 1024;
constexpr int Hh  = 16;
constexpr int HDd = 64;

// 0.125 (softmax scale) * log2(e), folded into Q at the QKV epilogue
#define QSCALE 0.18033688011112042f

typedef __attribute__((ext_vector_type(8))) _Float16 f16x8;
typedef __attribute__((ext_vector_type(2))) __fp16   fp16x2;
typedef __attribute__((ext_vector_type(4))) float    f32x4;

__device__ inline unsigned short f2h(float f) {    // f32 -> f16 RTN
  _Float16 h = (_Float16)f;
  union { _Float16 h; unsigned short u; } v; v.h = h; return v.u;
}
__device__ inline unsigned cvt_pk_f16(float x, float y) {  // 2xf32 -> packed f16 (RTZ)
  union { fp16x2 h; unsigned u; } v;
  v.h = __builtin_amdgcn_cvt_pkrtz(x, y);
  return v.u;
}
// Single-instruction exp2
__device__ inline float fexp2(float x) {
  float r;
  asm("v_exp_f32 %0, %1" : "=v"(r) : "v"(x));
  return r;
}
__device__ inline void gload16(const void* g, void* l) {
  __builtin_amdgcn_global_load_lds((const __attribute__((address_space(1))) void*)g,
                                   (__attribute__((address_space(3))) void*)l, 16, 0, 0);
}

// ---------------------------------------------------------------------------
// Fused prep: blocks [0,2048) xcast; [2048,2816) w_qkv T+cast; [2816,3072) w_proj
// ---------------------------------------------------------------------------
__global__ __launch_bounds__(256) void prep(
    const float* __restrict__ X, const float* __restrict__ Wq,
    const float* __restrict__ Wp,
    unsigned short* __restrict__ Xf, unsigned short* __restrict__ Bqt,
    unsigned short* __restrict__ Bpt)
{
  const int bid = blockIdx.x;
  const int t = threadIdx.x;

  if (bid < 2048) {   // ---- xcast: 8 f32 -> f16 per thread
    const size_t i = ((size_t)bid * 256 + t) * 8;
    float4 u0 = *(const float4*)(X + i);
    float4 u1 = *(const float4*)(X + i + 4);
    ushort4 a, b;
    a.x = f2h(u0.x); a.y = f2h(u0.y); a.z = f2h(u0.z); a.w = f2h(u0.w);
    b.x = f2h(u1.x); b.y = f2h(u1.y); b.z = f2h(u1.z); b.w = f2h(u1.w);
    *(ushort4*)(Xf + i)     = a;
    *(ushort4*)(Xf + i + 4) = b;
    return;
  }

  __shared__ float T[64][65];
  const float* W; unsigned short* Wt; int Nd, n0, k0;
  if (bid < 2816) {
    const int b2 = bid - 2048;          // 768 blocks: 48 x 16
    W = Wq; Wt = Bqt; Nd = 3 * Dd;
    n0 = (b2 % 48) * 64; k0 = (b2 / 48) * 64;
  } else {
    const int b3 = bid - 2816;          // 256 blocks: 16 x 16
    W = Wp; Wt = Bpt; Nd = Dd;
    n0 = (b3 & 15) * 64; k0 = (b3 >> 4) * 64;
  }
  const int Kd = Dd;
#pragma unroll
  for (int i = 0; i < 4; ++i) {
    int idx = t + 256 * i;
    int r = idx >> 4, c4 = (idx & 15) * 4;
    float4 v = *(const float4*)(W + (size_t)(k0 + r) * Nd + n0 + c4);
    T[c4 + 0][r] = v.x; T[c4 + 1][r] = v.y;
    T[c4 + 2][r] = v.z; T[c4 + 3][r] = v.w;
  }
  __syncthreads();
#pragma unroll
  for (int i = 0; i < 4; ++i) {
    int idx = t + 256 * i;
    int nr = idx >> 4, kc = (idx & 15) * 4;
    ushort4 hv;
    hv.x = f2h(T[nr][kc + 0]); hv.y = f2h(T[nr][kc + 1]);
    hv.z = f2h(T[nr][kc + 2]); hv.w = f2h(T[nr][kc + 3]);
    *(ushort4*)(Wt + (size_t)(n0 + nr) * Kd + k0 + kc) = hv;
  }
}

// ---------------------------------------------------------------------------
// Single-f16 MFMA GEMM (R12 core), templated on tile-M:
//   BM=128: 128x128 tile, 4 waves as 2x2 (proven R12 config).
//   BM=64 :  64x128 tile, 4 waves as 1x4 col-groups -> 2x the blocks.
// BK=64, single-buffer LDS (8-chunk swizzle), (256,4).
// EPI 0: fp32 out Cout.  EPI 1 (BM=128 only): per-head f16 Qf/Kf
// (QSCALE on Q) + sigma-permuted Vtf.
// ---------------------------------------------------------------------------
template<int EPI, int BM>
__global__ __launch_bounds__(256, 4) void gemm_f16(
    const unsigned short* __restrict__ Ag,
    const unsigned short* __restrict__ Bg,
    const float* __restrict__ bias,
    float* __restrict__ Cout,
    unsigned short* __restrict__ Qf, unsigned short* __restrict__ Kf,
    unsigned short* __restrict__ Vtf,
    int Nsz, int Ksz, int gridM)
{
  __shared__ __align__(16) unsigned short A_s[BM * 64];  // BM rows x 64 k (f16)
  __shared__ __align__(16) unsigned short B_s[8192];     // 128 cols x 64 k

  constexpr int NBW = (BM == 128) ? 4 : 2; // b-frags per wave

  const int t    = threadIdx.x;
  const int lane = t & 63, w = t >> 6;
  const int g = lane >> 4, lid = lane & 15;
  const int wr = (BM == 128) ? (w >> 1) : 0;
  const int wcol0 = (BM == 128) ? ((w & 1) * 64) : (w * 32);

  const int nwg = gridDim.x;
  const int per = nwg >> 3;
  const int bid = (blockIdx.x & 7) * per + (blockIdx.x >> 3);
  const int by = bid % gridM, bx = bid / gridM;
  const int row0 = by * BM, col0 = bx * 128;

  f32x4 acc[4][NBW];
#pragma unroll
  for (int i = 0; i < 4; ++i)
#pragma unroll
    for (int j = 0; j < NBW; ++j) acc[i][j] = f32x4{0.f, 0.f, 0.f, 0.f};

  const int sg8 = ((lane & 7) ^ (lane >> 3)) * 8;  // pre-swizzled src chunk
  const int rl8 = lane >> 3;                        // row within octet

  for (int k0 = 0; k0 < Ksz; k0 += 64) {
    if (BM == 128) {
#pragma unroll
      for (int q = 0; q < 4; ++q) {
        const int oct = w * 4 + q;        // 0..15
        const int r = oct * 8 + rl8;      // 0..127
        gload16(Ag + (size_t)(row0 + r) * Ksz + k0 + sg8, A_s + oct * 512);
        gload16(Bg + (size_t)(col0 + r) * Ksz + k0 + sg8, B_s + oct * 512);
      }
    } else {
#pragma unroll
      for (int q = 0; q < 2; ++q) {       // A: 8 octets (64 rows)
        const int oct = w * 2 + q;
        const int r = oct * 8 + rl8;      // 0..63
        gload16(Ag + (size_t)(row0 + r) * Ksz + k0 + sg8, A_s + oct * 512);
      }
#pragma unroll
      for (int q = 0; q < 4; ++q) {       // B: 16 octets (128 cols)
        const int oct = w * 4 + q;
        const int r = oct * 8 + rl8;
        gload16(Bg + (size_t)(col0 + r) * Ksz + k0 + sg8, B_s + oct * 512);
      }
    }
    __syncthreads();

#pragma unroll
    for (int kk = 0; kk < 2; ++kk) {
      f16x8 a[4], b[NBW];
#pragma unroll
      for (int mb = 0; mb < 4; ++mb) {
        const int r = wr * 64 + mb * 16 + lid;
        const int off = r * 64 + (((kk * 4 + g) ^ (r & 7)) << 3);
        a[mb] = *(const f16x8*)(A_s + off);
      }
#pragma unroll
      for (int nb = 0; nb < NBW; ++nb) {
        const int c = wcol0 + nb * 16 + lid;
        const int off = c * 64 + (((kk * 4 + g) ^ (c & 7)) << 3);
        b[nb] = *(const f16x8*)(B_s + off);
      }
#pragma unroll
      for (int mb = 0; mb < 4; ++mb)
#pragma unroll
        for (int nb = 0; nb < NBW; ++nb)
          acc[mb][nb] = __builtin_amdgcn_mfma_f32_16x16x32_f16(a[mb], b[nb], acc[mb][nb], 0, 0, 0);
    }
    __syncthreads();
  }

#pragma unroll
  for (int nb = 0; nb < NBW; ++nb) {
    const int cg = col0 + wcol0 + nb * 16 + lid;
    const float bv = bias[cg];
    if (EPI == 0) {
#pragma unroll
      for (int mb = 0; mb < 4; ++mb)
#pragma unroll
        for (int reg = 0; reg < 4; ++reg) {
          int nrow = row0 + wr * 64 + mb * 16 + 4 * g + reg;
          Cout[(size_t)nrow * Nsz + cg] = acc[mb][nb][reg] + bv;
        }
    } else {
      const int region = cg >> 10;          // 0=Q 1=K 2=V
      const int h  = (cg & 1023) >> 6;
      const int hd = cg & 63;
      const int b2 = row0 >> 11;
      const int bh_ = b2 * Hh + h;
      const float sc = (region == 0) ? QSCALE : 1.0f;
#pragma unroll
      for (int mb = 0; mb < 4; ++mb) {
        const int nt0 = (row0 & 2047) + wr * 64 + mb * 16 + 4 * g;
        float cc[4];
#pragma unroll
        for (int reg = 0; reg < 4; ++reg) cc[reg] = (acc[mb][nb][reg] + bv) * sc;
        if (region == 2) {
          // sigma kv-permutation (nt0 is a multiple of 4, so the 4
          // consecutive kv stay contiguous: r-bits pass through)
          const int ns = (nt0 & ~31) | ((nt0 & 12) << 1) | ((nt0 & 16) >> 2);
          ushort4 vv;
          vv.x = f2h(cc[0]); vv.y = f2h(cc[1]);
          vv.z = f2h(cc[2]); vv.w = f2h(cc[3]);
          *(ushort4*)(Vtf + ((size_t)bh_ * HDd + hd) * Nn + ns) = vv;
        } else {
          unsigned short* P = (region == 0) ? Qf : Kf;
#pragma unroll
          for (int reg = 0; reg < 4; ++reg)
            P[((size_t)bh_ * Nn + nt0 + reg) * HDd + hd] = f2h(cc[reg]);
        }
      }
    }
  }
}

// ---------------------------------------------------------------------------
// MFMA flash attention, R19 (verified passing): P never touches LDS.
// QK^T C-layout (lane g holds kv = 64h + 16jb + 4g + reg for q = lid) is
// packed with cvt_pk into the PV A-fragment DIRECTLY; V's kv storage is
// sigma-permuted (at the QKV epilogue) so the B-fragment slot (g,j) holds
// the same kv.
// Dual q-strip per wave (shared K/V LDS reads), 4 waves, Q-tile 128,
// grid 512 (2 blocks/CU), KVBLK=128, dbuf, max-free softmax, ones-MFMA
// denominator, native v_exp_f32. LDS 64 KB.
// ---------------------------------------------------------------------------
__global__ __launch_bounds__(256, 2) void attn_mfma(
    const unsigned short* __restrict__ Qf, const unsigned short* __restrict__ Kf,
    const unsigned short* __restrict__ Vt,
    unsigned short* __restrict__ Of)
{
  __shared__ __align__(16) unsigned short Kf_s[16384];    // 2 x [128 kv][64 k]
  __shared__ __align__(16) unsigned short Vt_s[16384];    // 2 x [64 d][128 kv sigma]

  const int t    = threadIdx.x;
  const int lane = t & 63, w = t >> 6;        // 4 waves
  const int g    = lane >> 4, lid = lane & 15;

  const int hw = blockIdx.x;                  // 512 blocks
  const int bh = (hw & 7) * 4 + ((hw >> 3) & 3);
  const int q0 = (hw >> 5) * 128;             // 16 q-blocks per head
  const int b_ = bh >> 4, h_ = bh & 15;

  const size_t kvbase = (size_t)bh * Nn * HDd;

  // Hoisted Q for both strips (B-frag: col=lid, k=g*8+j)
  const int qrowA = q0 + w * 16 + lid;
  const unsigned short* qpA = Qf + kvbase + (size_t)qrowA * HDd + g * 8;
  f16x8 qa0 = *(const f16x8*)(qpA);
  f16x8 qa1 = *(const f16x8*)(qpA + 32);
  const unsigned short* qpB = qpA + (size_t)64 * HDd;
  f16x8 qb0 = *(const f16x8*)(qpB);
  f16x8 qb1 = *(const f16x8*)(qpB + 32);

  f16x8 vones;
#pragma unroll
  for (int i = 0; i < 8; ++i) vones[i] = (_Float16)1.0f;

  f32x4 oA[4], oB[4];
  f32x4 olA = f32x4{0.f, 0.f, 0.f, 0.f};
  f32x4 olB = f32x4{0.f, 0.f, 0.f, 0.f};
#pragma unroll
  for (int i = 0; i < 4; ++i) { oA[i] = f32x4{0.f,0.f,0.f,0.f}; oB[i] = f32x4{0.f,0.f,0.f,0.f}; }

  const int sg8 = ((lane & 7) ^ (lane >> 3)) * 8;  // K staging src chunk

  auto stage = [&](int buf, int kv0) {
#pragma unroll
    for (int q = 0; q < 8; ++q) {
      const int idx = w * 8 + q;            // 0..31 (wave-uniform branch)
      if (idx < 16) {                       // K: octet of 8 kv-rows
        const int r = idx * 8 + (lane >> 3);
        gload16(Kf + kvbase + (size_t)(kv0 + r) * HDd + sg8,
                Kf_s + buf * 8192 + idx * 512);
      } else {                              // V: quad of 4 d-rows, 16 chunks
        const int qd = idx - 16;
        const int r = qd * 4 + (lane >> 4);
        const int srcc = (lane & 15) ^ (r & 15);
        gload16(Vt + kvbase + (size_t)r * Nn + kv0 + srcc * 8,
                Vt_s + buf * 8192 + qd * 512);
      }
    }
  };

  stage(0, 0);
  int cur = 0;
  const int NT = Nn / 128;

  union PU { unsigned u[4]; f16x8 v; };

  for (int tt = 0; tt < NT; ++tt) {
    __syncthreads();   // buf[cur] staged; prior reads of buf[cur^1] done
    if (tt + 1 < NT) stage(cur ^ 1, (tt + 1) * 128);

    const int kb = cur * 8192;

    // ---- S = K Q^T for both strips; each K frag read once, used twice
    f32x4 sA[8], sB[8];
#pragma unroll
    for (int jbb = 0; jbb < 8; ++jbb) { sA[jbb] = f32x4{0.f,0.f,0.f,0.f}; sB[jbb] = f32x4{0.f,0.f,0.f,0.f}; }
    __builtin_amdgcn_s_setprio(1);
#pragma unroll
    for (int jbb = 0; jbb < 8; ++jbb) {
      const int row = jbb * 16 + lid;
      const int rs = kb + row * 64;
      const int sw = row & 7;
      f16x8 kf0 = *(const f16x8*)&Kf_s[rs + ((g       ^ sw)) * 8];
      f16x8 kf1 = *(const f16x8*)&Kf_s[rs + (((4 + g) ^ sw)) * 8];
      sA[jbb] = __builtin_amdgcn_mfma_f32_16x16x32_f16(kf0, qa0, sA[jbb], 0, 0, 0);
      sA[jbb] = __builtin_amdgcn_mfma_f32_16x16x32_f16(kf1, qa1, sA[jbb], 0, 0, 0);
      sB[jbb] = __builtin_amdgcn_mfma_f32_16x16x32_f16(kf0, qb0, sB[jbb], 0, 0, 0);
      sB[jbb] = __builtin_amdgcn_mfma_f32_16x16x32_f16(kf1, qb1, sB[jbb], 0, 0, 0);
    }
    __builtin_amdgcn_s_setprio(0);

    // ---- per 64-kv half: exp2, pack to A-frags in registers, PV
#pragma unroll
    for (int h = 0; h < 2; ++h) {
#pragma unroll
      for (int jb = 0; jb < 4; ++jb)
#pragma unroll
        for (int reg = 0; reg < 4; ++reg) {
          sA[h * 4 + jb][reg] = fexp2(sA[h * 4 + jb][reg]);
          sB[h * 4 + jb][reg] = fexp2(sB[h * 4 + jb][reg]);
        }

      // A-frag slot (g,j) = kv 64h + 16*(j>>2) + 4g + (j&3): lane-local.
      PU pA0, pA1, pB0, pB1;
#pragma unroll
      for (int jb = 0; jb < 2; ++jb) {
        pA0.u[2 * jb + 0] = cvt_pk_f16(sA[h * 4 + jb][0], sA[h * 4 + jb][1]);
        pA0.u[2 * jb + 1] = cvt_pk_f16(sA[h * 4 + jb][2], sA[h * 4 + jb][3]);
        pA1.u[2 * jb + 0] = cvt_pk_f16(sA[h * 4 + 2 + jb][0], sA[h * 4 + 2 + jb][1]);
        pA1.u[2 * jb + 1] = cvt_pk_f16(sA[h * 4 + 2 + jb][2], sA[h * 4 + 2 + jb][3]);
        pB0.u[2 * jb + 0] = cvt_pk_f16(sB[h * 4 + jb][0], sB[h * 4 + jb][1]);
        pB0.u[2 * jb + 1] = cvt_pk_f16(sB[h * 4 + jb][2], sB[h * 4 + jb][3]);
        pB1.u[2 * jb + 0] = cvt_pk_f16(sB[h * 4 + 2 + jb][0], sB[h * 4 + 2 + jb][1]);
        pB1.u[2 * jb + 1] = cvt_pk_f16(sB[h * 4 + 2 + jb][2], sB[h * 4 + 2 + jb][3]);
      }

      __builtin_amdgcn_s_setprio(1);
      olA = __builtin_amdgcn_mfma_f32_16x16x32_f16(pA0.v, vones, olA, 0, 0, 0);
      olA = __builtin_amdgcn_mfma_f32_16x16x32_f16(pA1.v, vones, olA, 0, 0, 0);
      olB = __builtin_amdgcn_mfma_f32_16x16x32_f16(pB0.v, vones, olB, 0, 0, 0);
      olB = __builtin_amdgcn_mfma_f32_16x16x32_f16(pB1.v, vones, olB, 0, 0, 0);
#pragma unroll
      for (int cb = 0; cb < 4; ++cb) {
        const int vrow = cb * 16 + lid;
        const int vs = kb + vrow * 128;
        const int sw = vrow & 15;
        f16x8 vb0 = *(const f16x8*)&Vt_s[vs + (((8 * h + g)     ^ sw)) * 8];
        f16x8 vb1 = *(const f16x8*)&Vt_s[vs + (((8 * h + 4 + g) ^ sw)) * 8];
        oA[cb] = __builtin_amdgcn_mfma_f32_16x16x32_f16(pA0.v, vb0, oA[cb], 0, 0, 0);
        oA[cb] = __builtin_amdgcn_mfma_f32_16x16x32_f16(pA1.v, vb1, oA[cb], 0, 0, 0);
        oB[cb] = __builtin_amdgcn_mfma_f32_16x16x32_f16(pB0.v, vb0, oB[cb], 0, 0, 0);
        oB[cb] = __builtin_amdgcn_mfma_f32_16x16x32_f16(pB1.v, vb1, oB[cb], 0, 0, 0);
      }
      __builtin_amdgcn_s_setprio(0);
    }
    cur ^= 1;
  }

  // ---- epilogue: normalize both strips (l in row layout from ones-MFMA)
  const size_t obaseA = ((size_t)(b_ * Nn + q0 + w * 16)) * Dd + h_ * 64;
  const size_t obaseB = obaseA + (size_t)64 * Dd;
#pragma unroll
  for (int reg = 0; reg < 4; ++reg) {
    const int row = 4 * g + reg;
    const float ivA = 1.0f / olA[reg];
    const float ivB = 1.0f / olB[reg];
#pragma unroll
    for (int cb = 0; cb < 4; ++cb) {
      Of[obaseA + (size_t)row * Dd + cb * 16 + lid] = f2h(oA[cb][reg] * ivA);
      Of[obaseB + (size_t)row * Dd + cb * 16 + lid] = f2h(oB[cb][reg] * ivB);
    }
  }
}

// ---------------------------------------------------------------------------
extern "C" void kernel_launch(void* const* d_in, const int* in_sizes, int n_in,
                              void* d_out, int out_size, void* d_ws, size_t ws_size,
                              hipStream_t stream)
{
  const float* x      = (const float*)d_in[0];
  const float* w_qkv  = (const float*)d_in[1];
  const float* b_qkv  = (const float*)d_in[2];
  const float* w_proj = (const float*)d_in[3];
  const float* b_proj = (const float*)d_in[4];
  float* outp = (float*)d_out;

  unsigned char* ws = (unsigned char*)d_ws;
  const size_t MB = 1ull << 20;
  unsigned short* Xf  = (unsigned short*)(ws +  0 * MB);  // 8 MB f16
  unsigned short* Bqt = (unsigned short*)(ws +  8 * MB);  // 6 MB f16 [3072][1024]
  unsigned short* Qf  = (unsigned short*)(ws + 14 * MB);  // 8 MB
  unsigned short* Kf  = (unsigned short*)(ws + 22 * MB);  // 8 MB
  unsigned short* Vtf = (unsigned short*)(ws + 30 * MB);  // 8 MB (sigma-permuted kv)
  unsigned short* Ofb = (unsigned short*)(ws + 38 * MB);  // 8 MB
  unsigned short* Bpt = (unsigned short*)(ws + 46 * MB);  // 2 MB [1024][1024]

  const int M = Bb * Nn;  // 4096

  // 1) fused prep: x->f16, w_qkv/w_proj -> transposed f16
  prep<<<dim3(3072), 256, 0, stream>>>(x, w_qkv, w_proj, Xf, Bqt, Bpt);

  // 2) QKV GEMM (128x128 tiles, 768 blocks = 3/CU) -> per-head Qf/Kf/Vtf
  gemm_f16<1, 128><<<dim3((3 * Dd / 128) * (M / 128)), 256, 0, stream>>>(
      Xf, Bqt, b_qkv, nullptr, Qf, Kf, Vtf, 3 * Dd, Dd, M / 128);

  // 3) flash attention -> Of (f16); 512 blocks x 256 threads, Q-tile 128
  attn_mfma<<<dim3((Nn / 128) * Bb * Hh), 256, 0, stream>>>(Qf, Kf, Vtf, Ofb);

  // 4) proj GEMM (64x128 tiles, 512 blocks = 2/CU) -> fp32 out
  gemm_f16<0, 64><<<dim3((Dd / 128) * (M / 64)), 256, 0, stream>>>(
      Ofb, Bpt, b_proj, outp, nullptr, nullptr, nullptr, Dd, Dd, M / 64);
}